// Round 5
// baseline (88.433 us; speedup 1.0000x reference)
//
#include <hip/hip_runtime.h>

typedef float f4 __attribute__((ext_vector_type(4)));
typedef int   i4 __attribute__((ext_vector_type(4)));

constexpr int NB = 16;                 // batch
constexpr int NC = 4;                  // classes
constexpr int HW = 768 * 768;          // spatial M = 589824
constexpr int M4 = HW / 4;             // float4 chunks per image = 147456
constexpr int BLOCKS_PER_IMG = 96;     // 96*16 = 1536 blocks = 6/CU exactly (no tail round)
constexpr int CHUNK_STRIDE = BLOCKS_PER_IMG * 256;   // 24576
constexpr int ITERS = 6;               // 96*256*6 == M4 exactly, no remainder

// ws layout: ws[(n*8 + slot) * BLOCKS_PER_IMG + bx]
//   slot 0..3 = per-class num partial, slot 4..7 = per-class den partial
// Every entry is written every call -> no init/memset, no atomics.

__global__ __launch_bounds__(256, 6) void dice_partial(
    const float* __restrict__ predict,
    const int*   __restrict__ target,
    const int*   __restrict__ masks,
    float*       __restrict__ ws)
{
    const int n = blockIdx.y;
    const float* p = predict + (size_t)n * NC * HW;
    const f4* pc0 = (const f4*)(p);
    const f4* pc1 = (const f4*)(p + (size_t)HW);
    const f4* pc2 = (const f4*)(p + (size_t)2 * HW);
    const f4* pc3 = (const f4*)(p + (size_t)3 * HW);
    const i4* tg  = (const i4*)(target + (size_t)n * HW);
    const i4* mk  = (const i4*)(masks  + (size_t)n * HW);

    const int base = blockIdx.x * 256 + threadIdx.x;

    float num0 = 0.f, num1 = 0.f, num2 = 0.f, num3 = 0.f;
    float den0 = 0.f, den1 = 0.f, den2 = 0.f, den3 = 0.f;

#pragma unroll
    for (int k = 0; k < ITERS; ++k) {
        const int v = base + k * CHUNK_STRIDE;
        const f4 a = pc0[v];
        const f4 b = pc1[v];
        const f4 c = pc2[v];
        const f4 d = pc3[v];
        const i4 t = tg[v];
        const i4 m = mk[v];

#pragma unroll
        for (int j = 0; j < 4; ++j) {
            const float x0 = a[j], x1 = b[j], x2 = c[j], x3 = d[j];
            const int   tt = t[j];
            const bool  on = (m[j] >= 1);

            // softmax over the 4 classes; branchless mask select
            const float mx  = fmaxf(fmaxf(x0, x1), fmaxf(x2, x3));
            const float e0  = __expf(x0 - mx);
            const float e1  = __expf(x1 - mx);
            const float e2  = __expf(x2 - mx);
            const float e3  = __expf(x3 - mx);
            const float inv = 1.0f / (e0 + e1 + e2 + e3);
            const float s0  = e0 * inv, s1 = e1 * inv, s2 = e2 * inv, s3 = e3 * inv;

            const float oh0 = (tt == 0) ? 1.0f : 0.0f;
            const float oh1 = (tt == 1) ? 1.0f : 0.0f;
            const float oh2 = (tt == 2) ? 1.0f : 0.0f;
            const float oh3 = (tt == 3) ? 1.0f : 0.0f;

            const float f0 = on ? s0 : oh0;
            const float f1 = on ? s1 : oh1;
            const float f2 = on ? s2 : oh2;
            const float f3 = on ? s3 : oh3;

            num0 += f0 * oh0;  den0 += f0 * f0 + oh0;
            num1 += f1 * oh1;  den1 += f1 * f1 + oh1;
            num2 += f2 * oh2;  den2 += f2 * f2 + oh2;
            num3 += f3 * oh3;  den3 += f3 * f3 + oh3;
        }
    }

    // 64-lane wave reduction of the 8 partials
#pragma unroll
    for (int off = 32; off > 0; off >>= 1) {
        num0 += __shfl_down(num0, off);
        num1 += __shfl_down(num1, off);
        num2 += __shfl_down(num2, off);
        num3 += __shfl_down(num3, off);
        den0 += __shfl_down(den0, off);
        den1 += __shfl_down(den1, off);
        den2 += __shfl_down(den2, off);
        den3 += __shfl_down(den3, off);
    }

    __shared__ float sred[4][8];   // 4 waves per block
    const int wid  = threadIdx.x >> 6;
    const int lane = threadIdx.x & 63;
    if (lane == 0) {
        sred[wid][0] = num0; sred[wid][1] = num1; sred[wid][2] = num2; sred[wid][3] = num3;
        sred[wid][4] = den0; sred[wid][5] = den1; sred[wid][6] = den2; sred[wid][7] = den3;
    }
    __syncthreads();
    if (threadIdx.x < 8) {
        const float s = sred[0][threadIdx.x] + sred[1][threadIdx.x]
                      + sred[2][threadIdx.x] + sred[3][threadIdx.x];
        ws[(n * 8 + threadIdx.x) * BLOCKS_PER_IMG + blockIdx.x] = s;
    }
}

__global__ __launch_bounds__(1024) void dice_final(
    const float* __restrict__ ws, float* __restrict__ out)
{
    // 128 slot-rows (16 images x 8 slots), each a sum over 96 block partials.
    // 8 threads per row, 12 strided loads each -> parallel, no long serial chain.
    __shared__ float part[128][8];
    __shared__ float ssum[128];
    const int i   = threadIdx.x;        // 0..1023
    const int row = i >> 3;
    const int q   = i & 7;
    const float* r = ws + (size_t)row * BLOCKS_PER_IMG;
    float s = 0.f;
#pragma unroll
    for (int j = 0; j < 12; ++j) s += r[q + 8 * j];
    part[row][q] = s;
    __syncthreads();

    if (i < 128) {
        float t = 0.f;
#pragma unroll
        for (int k = 0; k < 8; ++k) t += part[i][k];
        ssum[i] = t;
    }
    __syncthreads();

    if (i < 64) {                       // lane i -> (n = i/4, c = i%4); NB*NC = 64
        const int n = i >> 2;
        const int c = i & 3;
        const float num = ssum[n * 8 + c]     + 1.0f;  // + SMOOTH
        const float den = ssum[n * 8 + 4 + c] + 1.0f;  // + SMOOTH
        float l = 1.0f - num / den;
#pragma unroll
        for (int off = 32; off > 0; off >>= 1) l += __shfl_down(l, off);
        if (i == 0) out[0] = l * (1.0f / (NB * NC));
    }
}

extern "C" void kernel_launch(void* const* d_in, const int* in_sizes, int n_in,
                              void* d_out, int out_size, void* d_ws, size_t ws_size,
                              hipStream_t stream) {
    const float* predict = (const float*)d_in[0];
    const int*   target  = (const int*)d_in[1];
    const int*   masks   = (const int*)d_in[2];
    float*       out     = (float*)d_out;
    float*       ws      = (float*)d_ws;

    dim3 grid(BLOCKS_PER_IMG, NB);
    dice_partial<<<grid, 256, 0, stream>>>(predict, target, masks, ws);
    dice_final<<<1, 1024, 0, stream>>>(ws, out);
}

// Round 6
// 41.205 us; speedup vs baseline: 2.1462x; 2.1462x over previous
//
#include <hip/hip_runtime.h>

typedef float f4 __attribute__((ext_vector_type(4)));
typedef int   i4 __attribute__((ext_vector_type(4)));

constexpr int NB = 16;                 // batch
constexpr int NC = 4;                  // classes
constexpr int HW = 768 * 768;          // spatial M = 589824
constexpr int M4 = HW / 4;             // float4 chunks per image = 147456
constexpr int BLOCKS_PER_IMG = 96;     // 96*16 = 1536 blocks = exactly 6/CU, single round
constexpr int CHUNK_STRIDE = BLOCKS_PER_IMG * 256;   // 24576
constexpr int ITERS = 6;               // 96*256*6 == M4 exactly, perfectly balanced

// ws layout: ws[(n*8 + slot) * BLOCKS_PER_IMG + bx]
//   slot 0..3 = per-class num partial, slot 4..7 = per-class den partial
// Every entry is written every call -> no init/memset, no atomics.
// NOTE: one-arg launch_bounds ONLY. The (256,6) variant in R5 capped VGPRs and
// spilled ~330 B/thread to scratch (WRITE_SIZE 0.6->131 MB, 2x dur regression).

__global__ __launch_bounds__(256) void dice_partial(
    const float* __restrict__ predict,
    const int*   __restrict__ target,
    const int*   __restrict__ masks,
    float*       __restrict__ ws)
{
    const int n = blockIdx.y;
    const float* p = predict + (size_t)n * NC * HW;
    const f4* pc0 = (const f4*)(p);
    const f4* pc1 = (const f4*)(p + (size_t)HW);
    const f4* pc2 = (const f4*)(p + (size_t)2 * HW);
    const f4* pc3 = (const f4*)(p + (size_t)3 * HW);
    const i4* tg  = (const i4*)(target + (size_t)n * HW);
    const i4* mk  = (const i4*)(masks  + (size_t)n * HW);

    const int base = blockIdx.x * 256 + threadIdx.x;

    float num0 = 0.f, num1 = 0.f, num2 = 0.f, num3 = 0.f;
    float den0 = 0.f, den1 = 0.f, den2 = 0.f, den3 = 0.f;

#pragma unroll
    for (int k = 0; k < ITERS; ++k) {
        const int v = base + k * CHUNK_STRIDE;
        const f4 a = pc0[v];
        const f4 b = pc1[v];
        const f4 c = pc2[v];
        const f4 d = pc3[v];
        const i4 t = tg[v];
        const i4 m = mk[v];

#pragma unroll
        for (int j = 0; j < 4; ++j) {
            const float x0 = a[j], x1 = b[j], x2 = c[j], x3 = d[j];
            const int   tt = t[j];
            const bool  on = (m[j] >= 1);

            // softmax over the 4 classes; branchless mask select
            const float mx  = fmaxf(fmaxf(x0, x1), fmaxf(x2, x3));
            const float e0  = __expf(x0 - mx);
            const float e1  = __expf(x1 - mx);
            const float e2  = __expf(x2 - mx);
            const float e3  = __expf(x3 - mx);
            const float inv = 1.0f / (e0 + e1 + e2 + e3);
            const float s0  = e0 * inv, s1 = e1 * inv, s2 = e2 * inv, s3 = e3 * inv;

            const float oh0 = (tt == 0) ? 1.0f : 0.0f;
            const float oh1 = (tt == 1) ? 1.0f : 0.0f;
            const float oh2 = (tt == 2) ? 1.0f : 0.0f;
            const float oh3 = (tt == 3) ? 1.0f : 0.0f;

            const float f0 = on ? s0 : oh0;
            const float f1 = on ? s1 : oh1;
            const float f2 = on ? s2 : oh2;
            const float f3 = on ? s3 : oh3;

            num0 += f0 * oh0;  den0 += f0 * f0 + oh0;
            num1 += f1 * oh1;  den1 += f1 * f1 + oh1;
            num2 += f2 * oh2;  den2 += f2 * f2 + oh2;
            num3 += f3 * oh3;  den3 += f3 * f3 + oh3;
        }
    }

    // 64-lane wave reduction of the 8 partials
#pragma unroll
    for (int off = 32; off > 0; off >>= 1) {
        num0 += __shfl_down(num0, off);
        num1 += __shfl_down(num1, off);
        num2 += __shfl_down(num2, off);
        num3 += __shfl_down(num3, off);
        den0 += __shfl_down(den0, off);
        den1 += __shfl_down(den1, off);
        den2 += __shfl_down(den2, off);
        den3 += __shfl_down(den3, off);
    }

    __shared__ float sred[4][8];   // 4 waves per block
    const int wid  = threadIdx.x >> 6;
    const int lane = threadIdx.x & 63;
    if (lane == 0) {
        sred[wid][0] = num0; sred[wid][1] = num1; sred[wid][2] = num2; sred[wid][3] = num3;
        sred[wid][4] = den0; sred[wid][5] = den1; sred[wid][6] = den2; sred[wid][7] = den3;
    }
    __syncthreads();
    if (threadIdx.x < 8) {
        const float s = sred[0][threadIdx.x] + sred[1][threadIdx.x]
                      + sred[2][threadIdx.x] + sred[3][threadIdx.x];
        ws[(n * 8 + threadIdx.x) * BLOCKS_PER_IMG + blockIdx.x] = s;
    }
}

__global__ __launch_bounds__(1024) void dice_final(
    const float* __restrict__ ws, float* __restrict__ out)
{
    // 128 slot-rows (16 images x 8 slots), each a sum over 96 block partials.
    // 8 threads per row, 12 strided loads each -> parallel, no long serial chain.
    __shared__ float part[128][8];
    __shared__ float ssum[128];
    const int i   = threadIdx.x;        // 0..1023
    const int row = i >> 3;
    const int q   = i & 7;
    const float* r = ws + (size_t)row * BLOCKS_PER_IMG;
    float s = 0.f;
#pragma unroll
    for (int j = 0; j < 12; ++j) s += r[q + 8 * j];
    part[row][q] = s;
    __syncthreads();

    if (i < 128) {
        float t = 0.f;
#pragma unroll
        for (int k = 0; k < 8; ++k) t += part[i][k];
        ssum[i] = t;
    }
    __syncthreads();

    if (i < 64) {                       // lane i -> (n = i/4, c = i%4); NB*NC = 64
        const int n = i >> 2;
        const int c = i & 3;
        const float num = ssum[n * 8 + c]     + 1.0f;  // + SMOOTH
        const float den = ssum[n * 8 + 4 + c] + 1.0f;  // + SMOOTH
        float l = 1.0f - num / den;
#pragma unroll
        for (int off = 32; off > 0; off >>= 1) l += __shfl_down(l, off);
        if (i == 0) out[0] = l * (1.0f / (NB * NC));
    }
}

extern "C" void kernel_launch(void* const* d_in, const int* in_sizes, int n_in,
                              void* d_out, int out_size, void* d_ws, size_t ws_size,
                              hipStream_t stream) {
    const float* predict = (const float*)d_in[0];
    const int*   target  = (const int*)d_in[1];
    const int*   masks   = (const int*)d_in[2];
    float*       out     = (float*)d_out;
    float*       ws      = (float*)d_ws;

    dim3 grid(BLOCKS_PER_IMG, NB);
    dice_partial<<<grid, 256, 0, stream>>>(predict, target, masks, ws);
    dice_final<<<1, 1024, 0, stream>>>(ws, out);
}

// Round 7
// 40.887 us; speedup vs baseline: 2.1629x; 1.0078x over previous
//
#include <hip/hip_runtime.h>

typedef float f4 __attribute__((ext_vector_type(4)));
typedef int   i4 __attribute__((ext_vector_type(4)));

constexpr int NB = 16;                 // batch
constexpr int NC = 4;                  // classes
constexpr int HW = 768 * 768;          // spatial M = 589824
constexpr int M4 = HW / 4;             // float4 chunks per image = 147456
// R6 ran VGPR=68 -> 4 waves/SIMD -> 4 blocks/CU resident (m69 steps at 64/128).
// Size the grid to that regime: 64 blocks/img * 16 = 1024 = exactly 4/CU, one round.
constexpr int BLOCKS_PER_IMG = 64;
constexpr int CHUNK_STRIDE = BLOCKS_PER_IMG * 256;   // 16384
constexpr int ITERS = 9;               // 64*256*9 == M4 exactly, no remainder

// ws layout: ws[(n*8 + slot) * BLOCKS_PER_IMG + bx]
//   slot 0..3 = per-class num partial, slot 4..7 = per-class den partial
// Every entry is written every call -> no init/memset, no atomics.
// NOTE: one-arg launch_bounds ONLY. Two-arg (256,6) in R5 made the allocator
// spill ~330 B/thread to scratch (WRITE_SIZE 0.6->131 MB, 2x regression).

__global__ __launch_bounds__(256) void dice_partial(
    const float* __restrict__ predict,
    const int*   __restrict__ target,
    const int*   __restrict__ masks,
    float*       __restrict__ ws)
{
    const int n = blockIdx.y;
    const float* p = predict + (size_t)n * NC * HW;
    const f4* pc0 = (const f4*)(p);
    const f4* pc1 = (const f4*)(p + (size_t)HW);
    const f4* pc2 = (const f4*)(p + (size_t)2 * HW);
    const f4* pc3 = (const f4*)(p + (size_t)3 * HW);
    const i4* tg  = (const i4*)(target + (size_t)n * HW);
    const i4* mk  = (const i4*)(masks  + (size_t)n * HW);

    const int base = blockIdx.x * 256 + threadIdx.x;

    float num0 = 0.f, num1 = 0.f, num2 = 0.f, num3 = 0.f;
    float den0 = 0.f, den1 = 0.f, den2 = 0.f, den3 = 0.f;

#pragma unroll
    for (int k = 0; k < ITERS; ++k) {
        const int v = base + k * CHUNK_STRIDE;
        const f4 a = pc0[v];
        const f4 b = pc1[v];
        const f4 c = pc2[v];
        const f4 d = pc3[v];
        const i4 t = tg[v];
        const i4 m = mk[v];

#pragma unroll
        for (int j = 0; j < 4; ++j) {
            const float x0 = a[j], x1 = b[j], x2 = c[j], x3 = d[j];
            const int   tt = t[j];
            const bool  on = (m[j] >= 1);

            // softmax over the 4 classes; branchless mask select
            const float mx  = fmaxf(fmaxf(x0, x1), fmaxf(x2, x3));
            const float e0  = __expf(x0 - mx);
            const float e1  = __expf(x1 - mx);
            const float e2  = __expf(x2 - mx);
            const float e3  = __expf(x3 - mx);
            const float inv = 1.0f / (e0 + e1 + e2 + e3);
            const float s0  = e0 * inv, s1 = e1 * inv, s2 = e2 * inv, s3 = e3 * inv;

            const float oh0 = (tt == 0) ? 1.0f : 0.0f;
            const float oh1 = (tt == 1) ? 1.0f : 0.0f;
            const float oh2 = (tt == 2) ? 1.0f : 0.0f;
            const float oh3 = (tt == 3) ? 1.0f : 0.0f;

            const float f0 = on ? s0 : oh0;
            const float f1 = on ? s1 : oh1;
            const float f2 = on ? s2 : oh2;
            const float f3 = on ? s3 : oh3;

            num0 += f0 * oh0;  den0 += f0 * f0 + oh0;
            num1 += f1 * oh1;  den1 += f1 * f1 + oh1;
            num2 += f2 * oh2;  den2 += f2 * f2 + oh2;
            num3 += f3 * oh3;  den3 += f3 * f3 + oh3;
        }
    }

    // 64-lane wave reduction of the 8 partials
#pragma unroll
    for (int off = 32; off > 0; off >>= 1) {
        num0 += __shfl_down(num0, off);
        num1 += __shfl_down(num1, off);
        num2 += __shfl_down(num2, off);
        num3 += __shfl_down(num3, off);
        den0 += __shfl_down(den0, off);
        den1 += __shfl_down(den1, off);
        den2 += __shfl_down(den2, off);
        den3 += __shfl_down(den3, off);
    }

    __shared__ float sred[4][8];   // 4 waves per block
    const int wid  = threadIdx.x >> 6;
    const int lane = threadIdx.x & 63;
    if (lane == 0) {
        sred[wid][0] = num0; sred[wid][1] = num1; sred[wid][2] = num2; sred[wid][3] = num3;
        sred[wid][4] = den0; sred[wid][5] = den1; sred[wid][6] = den2; sred[wid][7] = den3;
    }
    __syncthreads();
    if (threadIdx.x < 8) {
        const float s = sred[0][threadIdx.x] + sred[1][threadIdx.x]
                      + sred[2][threadIdx.x] + sred[3][threadIdx.x];
        ws[(n * 8 + threadIdx.x) * BLOCKS_PER_IMG + blockIdx.x] = s;
    }
}

__global__ __launch_bounds__(1024) void dice_final(
    const float* __restrict__ ws, float* __restrict__ out)
{
    // 128 slot-rows (16 images x 8 slots), each a sum over 64 block partials.
    // 8 threads per row, 8 strided loads each -> parallel, no serial chain.
    __shared__ float part[128][8];
    __shared__ float ssum[128];
    const int i   = threadIdx.x;        // 0..1023
    const int row = i >> 3;
    const int q   = i & 7;
    const float* r = ws + (size_t)row * BLOCKS_PER_IMG;
    float s = 0.f;
#pragma unroll
    for (int j = 0; j < 8; ++j) s += r[q + 8 * j];
    part[row][q] = s;
    __syncthreads();

    if (i < 128) {
        float t = 0.f;
#pragma unroll
        for (int k = 0; k < 8; ++k) t += part[i][k];
        ssum[i] = t;
    }
    __syncthreads();

    if (i < 64) {                       // lane i -> (n = i/4, c = i%4); NB*NC = 64
        const int n = i >> 2;
        const int c = i & 3;
        const float num = ssum[n * 8 + c]     + 1.0f;  // + SMOOTH
        const float den = ssum[n * 8 + 4 + c] + 1.0f;  // + SMOOTH
        float l = 1.0f - num / den;
#pragma unroll
        for (int off = 32; off > 0; off >>= 1) l += __shfl_down(l, off);
        if (i == 0) out[0] = l * (1.0f / (NB * NC));
    }
}

extern "C" void kernel_launch(void* const* d_in, const int* in_sizes, int n_in,
                              void* d_out, int out_size, void* d_ws, size_t ws_size,
                              hipStream_t stream) {
    const float* predict = (const float*)d_in[0];
    const int*   target  = (const int*)d_in[1];
    const int*   masks   = (const int*)d_in[2];
    float*       out     = (float*)d_out;
    float*       ws      = (float*)d_ws;

    dim3 grid(BLOCKS_PER_IMG, NB);
    dice_partial<<<grid, 256, 0, stream>>>(predict, target, masks, ws);
    dice_final<<<1, 1024, 0, stream>>>(ws, out);
}